// Round 6
// baseline (481.744 us; speedup 1.0000x reference)
//
#include <hip/hip_runtime.h>

// GcnEncoderGraph 2-dispatch pipeline. B=8, N=2048, DIN=32, DH=DE=64, R=3.
// R13: ONE cooperative mega-kernel with CUSTOM agent-scope barriers replaces
// the 5-dispatch dependent chain (cg::grid.sync measured ~90us/sync in R9;
// the done-counter fence pattern passed R10-12 -> hand-rolled barrier
// [threadfence + atomicAdd + relaxed spin + threadfence] should be ~2-5us).
// Also collapses launch gaps and makes kernel-side time visible as one
// >77us dispatch with full rocprof counters (everything was hidden below
// the 77us fill cutoff). Carries R12 content: rel-direct staging with
// virtual-K permutation (lane-contiguous loads, no over-fetch), nibble-LUT
// mask expansion, 2-barrier parallel combine, fused BN+xw, LDS tail.
// Dispatches: k_xw1 (768 blocks; also zeroes barrier counters),
//             k_mega (cooperative, 256x512): gemm1+bn1+gemm2+bn2+gemm3+tail.

#define NN 2048

typedef short short8 __attribute__((ext_vector_type(8)));
typedef float floatx4 __attribute__((ext_vector_type(4)));

__device__ __forceinline__ unsigned short f2bf(float x) {
  unsigned u = __float_as_uint(x);
  u += 0x7FFFu + ((u >> 16) & 1u);
  return (unsigned short)(u >> 16);
}

// physical node index k -> virtual K index (bijective per 1024-chunk)
__device__ __forceinline__ int kvirt(int k) {
  const int chunk = k >> 10, kin = k & 1023;
  return chunk * 1024 + ((kin >> 2) & 63) * 16 + ((kin >> 8) & 3) * 4 +
         (kin & 3);
}

// ---------- custom grid barrier (agent scope, 256 blocks) --------------------
// tid0: release fence -> arrival add -> relaxed spin (s_sleep, no per-poll
// cache inv) -> acquire fence. Same fence pattern as the proven done-counter
// tail (passed R10-12). Counters pre-zeroed by k_xw1 (dispatch before).
__device__ __forceinline__ void gbar(unsigned* ctr, int tid) {
  __syncthreads();
  if (tid == 0) {
    __threadfence();
    __hip_atomic_fetch_add(ctr, 1u, __ATOMIC_ACQ_REL,
                           __HIP_MEMORY_SCOPE_AGENT);
    while (__hip_atomic_load(ctr, __ATOMIC_RELAXED,
                             __HIP_MEMORY_SCOPE_AGENT) < 256u)
      __builtin_amdgcn_s_sleep(1);
    __threadfence();
  }
  __syncthreads();
}

// ---------- dispatch 1: XW precompute (layer 1) + zero barrier counters ------
__global__ __launch_bounds__(256) void k_xw1(const float* __restrict__ x,
                                             const float* __restrict__ w,
                                             unsigned short* __restrict__ xws,
                                             unsigned* __restrict__ ctrs) {
  __shared__ __align__(16) char smemc[16640];
  const int u = blockIdx.x, tid = threadIdx.x;
  if (u == 0 && tid < 128) ctrs[tid] = 0u;
  float* xs = (float*)smemc;                   // [64][33]
  float* wsh = (float*)(smemc + 64 * 33 * 4);  // [32][64]
  const int jc = u & 31, b = (u >> 5) & 7, r = u >> 8;
  const int j0 = jc * 64;
  for (int idx = tid; idx < 64 * 32; idx += 256) {
    int row = idx >> 5, f = idx & 31;
    xs[row * 33 + f] = x[((long)b * NN + j0 + row) * 32 + f];
    wsh[idx] = w[r * 2048 + idx];  // [f][e]
  }
  __syncthreads();
  const int j = tid & 63, g = tid >> 6;
  const int V = kvirt(j0 + j);  // virtual K position of this node
  const int kblk = V >> 5, kq = (V >> 3) & 3, kj = V & 7;
  unsigned short* dst =
      xws + (((long)(r * 8 + b) * 64 + kblk) * 4 + g) * 512 + kj;
  float xr[32];
#pragma unroll
  for (int f = 0; f < 32; ++f) xr[f] = xs[j * 33 + f];
#pragma unroll
  for (int ii = 0; ii < 16; ++ii) {
    float acc = 0.f;
#pragma unroll
    for (int f = 0; f < 32; ++f) acc += xr[f] * wsh[f * 64 + g * 16 + ii];
    dst[(kq * 16 + ii) * 8] = f2bf(acc);
  }
}

// ---------- shared epilogue: combine + bias + L2norm (+relu / pool) ----------
template <bool RELU, bool POOL3>
__device__ __forceinline__ void gemm_epilogue(
    char* smem, int b, int it, int tid, floatx4 (&acc)[4][4],
    const float* __restrict__ bias, float* __restrict__ Hout) {
  floatx4* cb = (floatx4*)smem;  // 64 KB combine buffer (overlay)
  const int wave = tid >> 6, lane = tid & 63;
  const int m = lane & 15, kq = lane >> 4;
  const int i0 = it * 64;
  // phase A — waves 4..7 write slots [rs][src][t][lane]
  if (wave >= 4) {
    const int src = wave - 4;
#pragma unroll
    for (int rs = 0; rs < 4; ++rs)
#pragma unroll
      for (int t = 0; t < 4; ++t)
        cb[((rs * 4 + src) * 4 + t) * 64 + lane] = acc[rs][t];
  }
  __syncthreads();
  // phase B — waves 0..3 fold their acc into their slot (exclusive RMW)
  if (wave < 4) {
#pragma unroll
    for (int rs = 0; rs < 4; ++rs)
#pragma unroll
      for (int t = 0; t < 4; ++t) {
        const int ix = ((rs * 4 + wave) * 4 + t) * 64 + lane;
        cb[ix] = cb[ix] + acc[rs][t];
      }
  }
  __syncthreads();
  // phase C — wave w sums 4 slots of rowset w, epilogue for its 16 rows
  if (wave < 4) {
    const int rs = wave;
    floatx4 s[4];
#pragma unroll
    for (int t = 0; t < 4; ++t) s[t] = cb[((rs * 4 + 0) * 4 + t) * 64 + lane];
#pragma unroll
    for (int src = 1; src < 4; ++src)
#pragma unroll
      for (int t = 0; t < 4; ++t)
        s[t] += cb[((rs * 4 + src) * 4 + t) * 64 + lane];
    float bv[4];
#pragma unroll
    for (int t = 0; t < 4; ++t) bv[t] = bias[t * 16 + m];
    float pmt[4] = {-3.4e38f, -3.4e38f, -3.4e38f, -3.4e38f};
#pragma unroll
    for (int reg = 0; reg < 4; ++reg) {
#pragma unroll
      for (int t = 0; t < 4; ++t) s[t][reg] += bv[t];
      float q = s[0][reg] * s[0][reg] + s[1][reg] * s[1][reg] +
                s[2][reg] * s[2][reg] + s[3][reg] * s[3][reg];
#pragma unroll
      for (int off = 1; off <= 8; off <<= 1) q += __shfl_xor(q, off);
      q = 1.0f / fmaxf(sqrtf(q), 1e-12f);
#pragma unroll
      for (int t = 0; t < 4; ++t) {
        float o = s[t][reg] * q;
        if (RELU) o = fmaxf(o, 0.0f);
        if (POOL3)
          pmt[t] = fmaxf(pmt[t], o);
        else
          Hout[((long)b * NN + i0 + rs * 16 + kq * 4 + reg) * 64 + t * 16 +
               m] = o;
      }
    }
    if (POOL3) {
#pragma unroll
      for (int t = 0; t < 4; ++t) {
        pmt[t] = fmaxf(pmt[t], __shfl_xor(pmt[t], 16));
        pmt[t] = fmaxf(pmt[t], __shfl_xor(pmt[t], 32));
      }
      float* pm = (float*)(smem + wave * 16384);
      if (kq == 0) {
#pragma unroll
        for (int t = 0; t < 4; ++t) pm[t * 16 + m] = pmt[t];
      }
    }
  }
}

// ---------- MFMA inner phase over one staged chunk ---------------------------
template <int NREL>
__device__ __forceinline__ void gemm_chunk_mfma(
    const unsigned* mw, const uint2* lut,
    const unsigned short* __restrict__ xws, int b, int chunk, int wave,
    int lane, floatx4 (&acc)[4][4]) {
  const int m = lane & 15, kq = lane >> 4;
  const unsigned shamt = kq * 8;
#pragma unroll
  for (int j = 0; j < 4; ++j) {
    const int kk = j * 8 + wave;       // chunk-local kblk
    const int kblk = chunk * 32 + kk;  // global kblk
#pragma unroll
    for (int p = 0; p < NREL; ++p) {
      const unsigned short* bb =
          xws + ((long)(p * 8 + b) * 64 + kblk) * 2048 + lane * 8;
      short8 bf0 = *(const short8*)(bb);
      short8 bf1 = *(const short8*)(bb + 512);
      short8 bf2 = *(const short8*)(bb + 1024);
      short8 bf3 = *(const short8*)(bb + 1536);
#pragma unroll
      for (int rs = 0; rs < 4; ++rs) {
        unsigned word = mw[(p * 64 + rs * 16 + m) * 33 + kk];
        unsigned byte = (word >> shamt) & 0xffu;
        uint2 lo = lut[byte & 15u];  // ds_read_b64, conflict-free
        uint2 hi = lut[byte >> 4];
        union {
          unsigned uu[4];
          short8 s8;
        } fr;
        fr.uu[0] = lo.x;
        fr.uu[1] = lo.y;
        fr.uu[2] = hi.x;
        fr.uu[3] = hi.y;
        acc[rs][0] = __builtin_amdgcn_mfma_f32_16x16x32_bf16(fr.s8, bf0,
                                                             acc[rs][0], 0, 0, 0);
        acc[rs][1] = __builtin_amdgcn_mfma_f32_16x16x32_bf16(fr.s8, bf1,
                                                             acc[rs][1], 0, 0, 0);
        acc[rs][2] = __builtin_amdgcn_mfma_f32_16x16x32_bf16(fr.s8, bf2,
                                                             acc[rs][2], 0, 0, 0);
        acc[rs][3] = __builtin_amdgcn_mfma_f32_16x16x32_bf16(fr.s8, bf3,
                                                             acc[rs][3], 0, 0, 0);
      }
    }
  }
}

// ---------- stage: layer-1 gemm, rel-direct (virtual-K staging) --------------
__device__ void dev_gemm_rel(char* smem, int bid, int tid,
                             const int* __restrict__ rel,
                             const unsigned short* __restrict__ xws,
                             const float* __restrict__ bias,
                             float* __restrict__ Hout,
                             unsigned* __restrict__ pu) {
  unsigned* mw = (unsigned*)smem;          // [3][64][33] mask words
  uint2* lut = (uint2*)(smem + 3 * 8448);  // 16 x 8B nibble->2x bf16-pair
  const int b = bid & 7, it = bid >> 3;
  const int wave = tid >> 6, lane = tid & 63;
  const int i0 = it * 64;

  if (tid < 16) {
    unsigned n = tid;
    lut[n] =
        make_uint2(((n & 1u) ? 0x3f80u : 0u) | ((n & 2u) ? 0x3f800000u : 0u),
                   ((n & 4u) ? 0x3f80u : 0u) | ((n & 8u) ? 0x3f800000u : 0u));
  }

  floatx4 acc[4][4];
#pragma unroll
  for (int rs = 0; rs < 4; ++rs)
#pragma unroll
    for (int t = 0; t < 4; ++t) acc[rs][t] = floatx4{0, 0, 0, 0};

  unsigned short* mh = (unsigned short*)mw;
  unsigned short* puh = (unsigned short*)pu;
  const long rowbase = (long)b * NN + i0;

  for (int chunk = 0; chunk < 2; ++chunk) {
    // ---- stage 64 rows (8/wave), pipelined one row ahead ----
    int4 v[4];
    {
      const int4* rp =
          (const int4*)(rel + (rowbase + wave * 8) * NN + chunk * 1024);
#pragma unroll
      for (int c = 0; c < 4; ++c) v[c] = rp[c * 64 + lane];
    }
#pragma unroll
    for (int rr = 0; rr < 8; ++rr) {
      const int row = wave * 8 + rr;
      int4 vn[4];
      if (rr < 7) {
        const int4* rp =
            (const int4*)(rel + (rowbase + row + 1) * NN + chunk * 1024);
#pragma unroll
        for (int c = 0; c < 4; ++c) vn[c] = rp[c * 64 + lane];
      }
      unsigned m0 = 0, m1 = 0, m2 = 0;
#pragma unroll
      for (int c = 0; c < 4; ++c) {
        int vv[4] = {v[c].x, v[c].y, v[c].z, v[c].w};
#pragma unroll
        for (int j = 0; j < 4; ++j) {
          unsigned bit = 1u << (c * 4 + j);
          m0 |= (vv[j] == 1) ? bit : 0u;
          m1 |= (vv[j] == 2) ? bit : 0u;
          m2 |= (vv[j] == 3) ? bit : 0u;
        }
      }
      const int hw = (row * 33 + (lane >> 1)) * 2 + (lane & 1);
      mh[hw] = (unsigned short)m0;
      mh[4224 + hw] = (unsigned short)m1;
      mh[8448 + hw] = (unsigned short)m2;
      puh[((rowbase + row) * 64 + chunk * 32) * 2 + lane] =
          (unsigned short)(m0 | m1 | m2);
#pragma unroll
      for (int c = 0; c < 4; ++c) v[c] = vn[c];
    }
    __syncthreads();
    gemm_chunk_mfma<3>(mw, lut, xws, b, chunk, wave, lane, acc);
    __syncthreads();
  }
  gemm_epilogue<true, false>(smem, b, it, tid, acc, bias, Hout);
}

// ---------- stage: union-plane gemm ------------------------------------------
template <bool RELU, bool POOL3>
__device__ void dev_gemm_u(char* smem, int bid, int tid,
                           const unsigned* __restrict__ pu,
                           const unsigned short* __restrict__ xws,
                           const float* __restrict__ bias,
                           float* __restrict__ Hout,
                           float* __restrict__ part3) {
  unsigned* mw = (unsigned*)smem;      // [64][33]
  uint2* lut = (uint2*)(smem + 8448);  // 16 x 8B
  const int b = bid & 7, it = bid >> 3;
  const int wave = tid >> 6, lane = tid & 63;
  const int i0 = it * 64;

  if (tid < 16) {
    unsigned n = tid;
    lut[n] =
        make_uint2(((n & 1u) ? 0x3f80u : 0u) | ((n & 2u) ? 0x3f800000u : 0u),
                   ((n & 4u) ? 0x3f80u : 0u) | ((n & 8u) ? 0x3f800000u : 0u));
  }

  floatx4 acc[4][4];
#pragma unroll
  for (int rs = 0; rs < 4; ++rs)
#pragma unroll
    for (int t = 0; t < 4; ++t) acc[rs][t] = floatx4{0, 0, 0, 0};

  for (int chunk = 0; chunk < 2; ++chunk) {
    for (int idx = tid; idx < 2048; idx += 512) {
      int row = idx >> 5, w = idx & 31;
      mw[row * 33 + w] = pu[((long)b * NN + i0 + row) * 64 + chunk * 32 + w];
    }
    __syncthreads();
    gemm_chunk_mfma<1>(mw, lut, xws, b, chunk, wave, lane, acc);
    __syncthreads();
  }
  gemm_epilogue<RELU, POOL3>(smem, b, it, tid, acc, bias, Hout);

  if (POOL3) {
    __syncthreads();
    if (tid < 64) {
      float v = -3.4e38f;
#pragma unroll
      for (int w = 0; w < 4; ++w)
        v = fmaxf(v, ((const float*)(smem + w * 16384))[tid]);
      part3[((long)b * 32 + it) * 64 + tid] = v;
    }
  }
}

// ---------- stage: fused BN + xw_h (+pool partial from b==0 blocks), 512 thr -
__device__ void dev_xwh_bn512(char* smemc, int bid, int tid,
                              const float* __restrict__ H,
                              const float* __restrict__ w,
                              unsigned short* __restrict__ xws,
                              float* __restrict__ PP) {
  float* hs = (float*)smemc;                    // [64][65]
  float* wsh = (float*)(smemc + 16640);         // [64][64]
  float* sm = (float*)(smemc + 16640 + 16384);  // [64]
  float* srs = (float*)(smemc + 16640 + 16384 + 256);
  const int jc = bid & 31, b = bid >> 5;
  const int j0 = jc * 64;
  // pass 1: stats. thread t: node n=t>>3, octant o=t&7 (8 e each, all 8 bb)
  {
    const int n = tid >> 3, o = tid & 7;
    float s1 = 0.f, s2 = 0.f;
#pragma unroll
    for (int bb = 0; bb < 8; ++bb) {
      const float4* hp =
          (const float4*)(H + ((long)bb * NN + j0 + n) * 64 + o * 8);
#pragma unroll
      for (int c = 0; c < 2; ++c) {
        float4 v = hp[c];
        s1 += v.x + v.y + v.z + v.w;
        s2 += v.x * v.x + v.y * v.y + v.z * v.z + v.w * v.w;
      }
    }
    s1 += __shfl_xor(s1, 1);
    s2 += __shfl_xor(s2, 1);
    s1 += __shfl_xor(s1, 2);
    s2 += __shfl_xor(s2, 2);
    s1 += __shfl_xor(s1, 4);
    s2 += __shfl_xor(s2, 4);
    if (o == 0) {
      float mean = s1 * (1.0f / 512.0f);
      float var = fmaxf(s2 * (1.0f / 512.0f) - mean * mean, 0.0f);
      sm[n] = mean;
      srs[n] = rsqrtf(var + 1e-5f);
    }
  }
  __syncthreads();
  // pass 2: normalized tile for our b + weights
  for (int idx = tid; idx < 4096; idx += 512) {
    int row = idx >> 6, f = idx & 63;
    float v = H[((long)b * NN + j0 + row) * 64 + f];
    hs[row * 65 + f] = (v - sm[row]) * srs[row];
    wsh[idx] = w[idx];
  }
  __syncthreads();
  // pass 3: xw into swizzled fragment layout (virtual-K position)
  {
    const int j = tid & 63, gg = tid >> 6;
    const int g = gg & 3, hf = gg >> 2;
    const int V = kvirt(j0 + j);
    const int kblk = V >> 5, kq = (V >> 3) & 3, kj = V & 7;
    unsigned short* dst = xws + (((long)b * 64 + kblk) * 4 + g) * 512 + kj;
    float acc[8];
#pragma unroll
    for (int ii = 0; ii < 8; ++ii) acc[ii] = 0.f;
#pragma unroll
    for (int c = 0; c < 4; ++c) {
      float xr[16];
#pragma unroll
      for (int f = 0; f < 16; ++f) xr[f] = hs[j * 65 + c * 16 + f];
#pragma unroll
      for (int ii = 0; ii < 8; ++ii)
#pragma unroll
        for (int f = 0; f < 16; ++f)
          acc[ii] += xr[f] * wsh[(c * 16 + f) * 64 + g * 16 + hf * 8 + ii];
    }
#pragma unroll
    for (int ii = 0; ii < 8; ++ii)
      dst[(kq * 16 + hf * 8 + ii) * 8] = f2bf(acc[ii]);
  }
  // pass 4 (b==0 blocks): pool partials over our 64 nodes, all (bb,e)
  if (b == 0) {
    const int col = tid;  // 512 = 8 bb x 64 e
    const int bb = col >> 6, e = col & 63;
    float mx = -3.4e38f;
    for (int n = 0; n < 64; ++n) {
      float v = H[((long)bb * NN + j0 + n) * 64 + e];
      mx = fmaxf(mx, (v - sm[n]) * srs[n]);
    }
    PP[(long)jc * 512 + col] = mx;
  }
}

// ---------- stage: pool finals + linear head (block 0 only) ------------------
__device__ void dev_tail(char* smemc, int tid, const float* __restrict__ PP1,
                         const float* __restrict__ PP2,
                         const float* __restrict__ P3, float* __restrict__ out,
                         const float* __restrict__ wmap,
                         const float* __restrict__ bmap) {
  float* obuf = (float*)smemc;  // [8][192]
  const int col = tid;
  const int bb = col >> 6, e = col & 63;
  float m1 = -3.4e38f, m2 = -3.4e38f, m3 = -3.4e38f;
#pragma unroll
  for (int c = 0; c < 32; ++c) {
    m1 = fmaxf(m1, PP1[(long)c * 512 + col]);
    m2 = fmaxf(m2, PP2[(long)c * 512 + col]);
    m3 = fmaxf(m3, P3[((long)bb * 32 + c) * 64 + e]);
  }
  out[bb * 192 + e] = m1;
  out[bb * 192 + 64 + e] = m2;
  out[bb * 192 + 128 + e] = m3;
  obuf[bb * 192 + e] = m1;
  obuf[bb * 192 + 64 + e] = m2;
  obuf[bb * 192 + 128 + e] = m3;
  __syncthreads();
  float acc = bmap[e];
#pragma unroll 4
  for (int k = 0; k < 192; ++k) acc += obuf[bb * 192 + k] * wmap[k * 64 + e];
  out[1536 + bb * 64 + e] = acc;
}

// ---------- dispatch 2: the cooperative mega-kernel --------------------------
__global__ __launch_bounds__(512) void k_mega(
    const int* __restrict__ rel, const unsigned short* __restrict__ xws_c,
    unsigned short* __restrict__ xws, const float* __restrict__ b_first,
    const float* __restrict__ w_block, const float* __restrict__ b_block,
    const float* __restrict__ w_last, const float* __restrict__ b_last,
    const float* __restrict__ wmap, const float* __restrict__ bmap,
    unsigned* __restrict__ pu, float* __restrict__ H,
    float* __restrict__ PP1, float* __restrict__ PP2,
    float* __restrict__ PART3, float* __restrict__ out,
    unsigned* __restrict__ ctrs) {
  __shared__ __align__(16) char smem[65536];
  const int bid = blockIdx.x, tid = threadIdx.x;

  // layer 1: rel-direct gemm (writes H + union plane)
  dev_gemm_rel(smem, bid, tid, rel, xws_c, b_first, H, pu);
  gbar(&ctrs[0], tid);
  // bn1 + xw(layer2) + PP1 partials
  dev_xwh_bn512(smem, bid, tid, H, w_block, xws, PP1);
  gbar(&ctrs[16], tid);
  // layer 2 gemm
  dev_gemm_u<true, false>(smem, bid, tid, pu, xws_c, b_block, H, nullptr);
  gbar(&ctrs[32], tid);
  // bn2 + xw(layer3) + PP2 partials
  dev_xwh_bn512(smem, bid, tid, H, w_last, xws, PP2);
  gbar(&ctrs[48], tid);
  // layer 3 gemm (pool3 partials)
  dev_gemm_u<false, true>(smem, bid, tid, pu, xws_c, b_last, nullptr, PART3);
  gbar(&ctrs[64], tid);
  // pool finals + head
  if (bid == 0) dev_tail(smem, tid, PP1, PP2, PART3, out, wmap, bmap);
}

extern "C" void kernel_launch(void* const* d_in, const int* in_sizes, int n_in,
                              void* d_out, int out_size, void* d_ws,
                              size_t ws_size, hipStream_t stream) {
  const float* x = (const float*)d_in[0];
  const int* rel = (const int*)d_in[1];
  // d_in[2] (adj) unread: adj == (rel > 0) == union bitplane
  const float* w_first = (const float*)d_in[3];
  const float* b_first = (const float*)d_in[4];
  const float* w_block = (const float*)d_in[5];
  const float* b_block = (const float*)d_in[6];
  const float* w_last = (const float*)d_in[7];
  const float* b_last = (const float*)d_in[8];
  const float* w_map = (const float*)d_in[9];
  const float* b_map = (const float*)d_in[10];
  float* out = (float*)d_out;

  char* ws = (char*)d_ws;
  const size_t MB = 1024 * 1024;
  unsigned* PU = (unsigned*)(ws);                        // 4 MiB union plane
  unsigned short* XWS = (unsigned short*)(ws + 4 * MB);  // 6 MiB
  float* H = (float*)(ws + 10 * MB);                     // 4 MiB
  float* PP1 = (float*)(ws + 14 * MB);                   // 64 KiB
  float* PP2 = (float*)(ws + 15 * MB);                   // 64 KiB
  float* PART3 = (float*)(ws + 16 * MB);                 // 64 KiB
  unsigned* CTRS = (unsigned*)(ws + 17 * MB);            // 512 B counters

  // ---- XW(layer1) precompute (also zeroes barrier counters) ----
  k_xw1<<<768, 256, 0, stream>>>(x, w_first, XWS, CTRS);
  // ---- everything else: one cooperative kernel, 5 custom barriers ----
  const unsigned short* XWS_C = XWS;
  void* kargs[] = {&rel,  &XWS_C,  &XWS,   &b_first, &w_block, &b_block,
                   &w_last, &b_last, &w_map, &b_map,   &PU,      &H,
                   &PP1,    &PP2,    &PART3, &out,     &CTRS};
  hipLaunchCooperativeKernel((void*)k_mega, dim3(256), dim3(512), kargs, 0,
                             stream);
}

// Round 7
// 384.463 us; speedup vs baseline: 1.2530x; 1.2530x over previous
//
#include <hip/hip_runtime.h>

// GcnEncoderGraph multi-kernel pipeline. B=8, N=2048, DIN=32, DH=DE=64, R=3.
// R14: revert to multi-dispatch (R13 priced custom grid barriers at ~27us
// each vs ~5us dispatch gaps; cg sync was 90us — both fusions dead).
// Structure = best-measured R8 skeleton + three theory-backed fixes:
// (1) pack kernel (4096 blocks, full-BW rel stream) now uses R12's
//     lane-contiguous virtual-K loads — kills the 4x sector over-fetch
//     measured in R11 (FETCH 527MB) while keeping streaming parallelism;
// (2) gemms stage masks in ONE pass ([NREL][64][66] words, 50.7KB LDS):
//     one stage + one MFMA phase, half the sync boundaries;
// (3) tail fused into gemm3 via done-counter (proven R10-R13).
// Virtual K index v = kvirt(k) applied consistently to mask bits (pack) and
// XW rows (xw1 / xwh_bn) — masked GEMM invariant under K-permutation.
// 6 dispatches: pack+xw1, gemm1, bn1, gemm2, bn2, gemm3+tail.

#define NN 2048
#define PLANE_W 1048576L  // u32 words per bitplane: 8*2048*64

typedef short short8 __attribute__((ext_vector_type(8)));
typedef float floatx4 __attribute__((ext_vector_type(4)));

__device__ __forceinline__ unsigned short f2bf(float x) {
  unsigned u = __float_as_uint(x);
  u += 0x7FFFu + ((u >> 16) & 1u);
  return (unsigned short)(u >> 16);
}

// physical node index k -> virtual K index (bijective per 1024-chunk)
__device__ __forceinline__ int kvirt(int k) {
  const int chunk = k >> 10, kin = k & 1023;
  return chunk * 1024 + ((kin >> 2) & 63) * 16 + ((kin >> 8) & 3) * 4 +
         (kin & 3);
}

// ---------- XW precompute (layer 1), swizzled B-fragment order, 256 thr ------
__device__ void dev_xw_first(char* smemc, int u, int tid,
                             const float* __restrict__ x,
                             const float* __restrict__ w,
                             unsigned short* __restrict__ xws) {
  float* xs = (float*)smemc;                   // [64][33]
  float* wsh = (float*)(smemc + 64 * 33 * 4);  // [32][64]
  const int jc = u & 31, b = (u >> 5) & 7, r = u >> 8;
  const int j0 = jc * 64;
  for (int idx = tid; idx < 64 * 32; idx += 256) {
    int row = idx >> 5, f = idx & 31;
    xs[row * 33 + f] = x[((long)b * NN + j0 + row) * 32 + f];
    wsh[idx] = w[r * 2048 + idx];  // [f][e]
  }
  __syncthreads();
  const int j = tid & 63, g = tid >> 6;
  const int V = kvirt(j0 + j);  // virtual K position of this node
  const int kblk = V >> 5, kq = (V >> 3) & 3, kj = V & 7;
  unsigned short* dst =
      xws + (((long)(r * 8 + b) * 64 + kblk) * 4 + g) * 512 + kj;
  float xr[32];
#pragma unroll
  for (int f = 0; f < 32; ++f) xr[f] = xs[j * 33 + f];
#pragma unroll
  for (int ii = 0; ii < 16; ++ii) {
    float acc = 0.f;
#pragma unroll
    for (int f = 0; f < 32; ++f) acc += xr[f] * wsh[f * 64 + g * 16 + ii];
    dst[(kq * 16 + ii) * 8] = f2bf(acc);
  }
  __syncthreads();
}

// ---------- kernel 1: streaming pack (virtual-K, lane-contiguous) + xw1 ------
// 4096 blocks x 256 thr. Wave gwid handles one full rel row (two 1024-edge
// chunks): per chunk, lane l does 4 lane-contiguous int4 loads (each
// instruction = 1KB dense across the wave -> no sector over-fetch), packs its
// 16 edges into one halfword per plane (virtual bit order), writes planes
// 0..2 + union plane 3 as coalesced halfwords. Blocks <768 also run xw1.
__global__ __launch_bounds__(256) void k_pack_xw1(
    const int* __restrict__ rel, unsigned* __restrict__ planes,
    const float* __restrict__ x, const float* __restrict__ w,
    unsigned short* __restrict__ xws, unsigned* __restrict__ done) {
  __shared__ __align__(16) char smemc[16640];
  const int bid = blockIdx.x, tid = threadIdx.x;
  if (bid == 0 && tid == 0) *done = 0u;
  if (bid < 768) dev_xw_first(smemc, bid, tid, x, w, xws);
  unsigned short* ph = (unsigned short*)planes;
  const int wave = tid >> 6, lane = tid & 63;
  const int gwid = bid * 4 + wave;  // [0, 16384)
#pragma unroll
  for (int s = 0; s < 2; ++s) {
    const int u = gwid * 2 + s;  // [0, 32768) row-chunks
    const int chunk = u & 1;
    const long bi = u >> 1;  // b*2048 + i
    const int4* rp = (const int4*)(rel + bi * NN + chunk * 1024);
    int4 v[4];
#pragma unroll
    for (int c = 0; c < 4; ++c) v[c] = rp[c * 64 + lane];
    unsigned m0 = 0, m1 = 0, m2 = 0;
#pragma unroll
    for (int c = 0; c < 4; ++c) {
      int vv[4] = {v[c].x, v[c].y, v[c].z, v[c].w};
#pragma unroll
      for (int j = 0; j < 4; ++j) {
        unsigned bit = 1u << (c * 4 + j);
        m0 |= (vv[j] == 1) ? bit : 0u;
        m1 |= (vv[j] == 2) ? bit : 0u;
        m2 |= (vv[j] == 3) ? bit : 0u;
      }
    }
    const long h = (bi * 64 + chunk * 32) * 2 + lane;  // halfword index
    ph[h] = (unsigned short)m0;
    ph[2 * PLANE_W + h] = (unsigned short)m1;
    ph[4 * PLANE_W + h] = (unsigned short)m2;
    ph[6 * PLANE_W + h] = (unsigned short)(m0 | m1 | m2);  // union
  }
}

// ---------- shared epilogue: combine + bias + L2norm (+relu / pool) ----------
template <bool RELU, bool POOL3>
__device__ __forceinline__ void gemm_epilogue(
    char* smem, int b, int it, int tid, floatx4 (&acc)[4][4],
    const float* __restrict__ bias, float* __restrict__ Hout) {
  floatx4* cb = (floatx4*)smem;  // 64 KB combine buffer (overlay)
  const int wave = tid >> 6, lane = tid & 63;
  const int m = lane & 15, kq = lane >> 4;
  const int i0 = it * 64;
  // phase A — waves 4..7 write slots [rs][src][t][lane]
  if (wave >= 4) {
    const int src = wave - 4;
#pragma unroll
    for (int rs = 0; rs < 4; ++rs)
#pragma unroll
      for (int t = 0; t < 4; ++t)
        cb[((rs * 4 + src) * 4 + t) * 64 + lane] = acc[rs][t];
  }
  __syncthreads();
  // phase B — waves 0..3 fold their acc into their slot (exclusive RMW)
  if (wave < 4) {
#pragma unroll
    for (int rs = 0; rs < 4; ++rs)
#pragma unroll
      for (int t = 0; t < 4; ++t) {
        const int ix = ((rs * 4 + wave) * 4 + t) * 64 + lane;
        cb[ix] = cb[ix] + acc[rs][t];
      }
  }
  __syncthreads();
  // phase C — wave w sums 4 slots of rowset w, epilogue for its 16 rows
  if (wave < 4) {
    const int rs = wave;
    floatx4 s[4];
#pragma unroll
    for (int t = 0; t < 4; ++t) s[t] = cb[((rs * 4 + 0) * 4 + t) * 64 + lane];
#pragma unroll
    for (int src = 1; src < 4; ++src)
#pragma unroll
      for (int t = 0; t < 4; ++t)
        s[t] += cb[((rs * 4 + src) * 4 + t) * 64 + lane];
    float bv[4];
#pragma unroll
    for (int t = 0; t < 4; ++t) bv[t] = bias[t * 16 + m];
    float pmt[4] = {-3.4e38f, -3.4e38f, -3.4e38f, -3.4e38f};
#pragma unroll
    for (int reg = 0; reg < 4; ++reg) {
#pragma unroll
      for (int t = 0; t < 4; ++t) s[t][reg] += bv[t];
      float q = s[0][reg] * s[0][reg] + s[1][reg] * s[1][reg] +
                s[2][reg] * s[2][reg] + s[3][reg] * s[3][reg];
#pragma unroll
      for (int off = 1; off <= 8; off <<= 1) q += __shfl_xor(q, off);
      q = 1.0f / fmaxf(sqrtf(q), 1e-12f);
#pragma unroll
      for (int t = 0; t < 4; ++t) {
        float o = s[t][reg] * q;
        if (RELU) o = fmaxf(o, 0.0f);
        if (POOL3)
          pmt[t] = fmaxf(pmt[t], o);
        else
          Hout[((long)b * NN + i0 + rs * 16 + kq * 4 + reg) * 64 + t * 16 +
               m] = o;
      }
    }
    if (POOL3) {
#pragma unroll
      for (int t = 0; t < 4; ++t) {
        pmt[t] = fmaxf(pmt[t], __shfl_xor(pmt[t], 16));
        pmt[t] = fmaxf(pmt[t], __shfl_xor(pmt[t], 32));
      }
      // wave w finished reading its own 16KB quarter — reuse for partials
      float* pm = (float*)(smem + wave * 16384);
      if (kq == 0) {
#pragma unroll
        for (int t = 0; t < 4; ++t) pm[t * 16 + m] = pmt[t];
      }
    }
  }
}

// ---------- kernels 2/4/6: masked MFMA gemm, single-pass staging -------------
// 256 blocks x 512 thr; b = bid&7 (XCD affinity), it = bid>>3. Wave w covers
// kblks == w (mod 8). Masks [NREL][64][66] words staged in ONE pass (words
// coalesced; 66-stride -> conflict-free MFMA-phase reads: 16 distinct even
// banks, 4-lane same-address broadcast). Nibble-LUT bf16 expansion.
// POOL3: pool partials + fused last-block tail (done counter).
template <int NREL, bool RELU, bool POOL3>
__global__ __launch_bounds__(512) void k_gemm8(
    const unsigned* __restrict__ planes, const unsigned short* __restrict__ xws,
    const float* __restrict__ bias, float* __restrict__ Hout,
    float* __restrict__ part3, const float* __restrict__ PP1,
    const float* __restrict__ PP2, float* __restrict__ out,
    const float* __restrict__ wmap, const float* __restrict__ bmap,
    unsigned* __restrict__ done) {
  __shared__ __align__(16) char smem[65536];
  __shared__ int s_last;
  unsigned* mw = (unsigned*)smem;               // [NREL][64][66] words
  uint2* lut = (uint2*)(smem + NREL * 16896);   // 16 x 8B nibble LUT
  const int bid = blockIdx.x;
  const int b = bid & 7, it = bid >> 3;
  const int tid = threadIdx.x;
  const int wave = tid >> 6, lane = tid & 63;
  const int m = lane & 15, kq = lane >> 4;
  const unsigned shamt = kq * 8;
  const int i0 = it * 64;

  if (tid < 16) {
    unsigned n = tid;
    lut[n] =
        make_uint2(((n & 1u) ? 0x3f80u : 0u) | ((n & 2u) ? 0x3f800000u : 0u),
                   ((n & 4u) ? 0x3f80u : 0u) | ((n & 8u) ? 0x3f800000u : 0u));
  }

  floatx4 acc[4][4];  // [rowset][t]
#pragma unroll
  for (int rs = 0; rs < 4; ++rs)
#pragma unroll
    for (int t = 0; t < 4; ++t) acc[rs][t] = floatx4{0, 0, 0, 0};

  // ---- single-pass mask stage: NREL*64 rows x 64 words, coalesced ----
  for (int idx = tid; idx < NREL * 4096; idx += 512) {
    const int p = idx >> 12, rem = idx & 4095, row = rem >> 6, w = rem & 63;
    const long g = ((long)b * NN + i0 + row) * 64 + w;
    unsigned v;
    if (NREL == 3)
      v = planes[(long)p * PLANE_W + g];
    else
      v = planes[3 * PLANE_W + g];  // union plane
    mw[(p * 64 + row) * 66 + w] = v;
  }
  __syncthreads();

  // ---- MFMA phase over all 64 kblks ----
#pragma unroll 2
  for (int j = 0; j < 8; ++j) {
    const int kblk = j * 8 + wave;
#pragma unroll
    for (int p = 0; p < NREL; ++p) {
      const unsigned short* bb =
          xws + ((long)(p * 8 + b) * 64 + kblk) * 2048 + lane * 8;
      short8 bf0 = *(const short8*)(bb);
      short8 bf1 = *(const short8*)(bb + 512);
      short8 bf2 = *(const short8*)(bb + 1024);
      short8 bf3 = *(const short8*)(bb + 1536);
#pragma unroll
      for (int rs = 0; rs < 4; ++rs) {
        unsigned word = mw[(p * 64 + rs * 16 + m) * 66 + kblk];
        unsigned byte = (word >> shamt) & 0xffu;
        uint2 lo = lut[byte & 15u];  // ds_read_b64, conflict-free
        uint2 hi = lut[byte >> 4];
        union {
          unsigned uu[4];
          short8 s8;
        } fr;
        fr.uu[0] = lo.x;
        fr.uu[1] = lo.y;
        fr.uu[2] = hi.x;
        fr.uu[3] = hi.y;
        acc[rs][0] = __builtin_amdgcn_mfma_f32_16x16x32_bf16(fr.s8, bf0,
                                                             acc[rs][0], 0, 0, 0);
        acc[rs][1] = __builtin_amdgcn_mfma_f32_16x16x32_bf16(fr.s8, bf1,
                                                             acc[rs][1], 0, 0, 0);
        acc[rs][2] = __builtin_amdgcn_mfma_f32_16x16x32_bf16(fr.s8, bf2,
                                                             acc[rs][2], 0, 0, 0);
        acc[rs][3] = __builtin_amdgcn_mfma_f32_16x16x32_bf16(fr.s8, bf3,
                                                             acc[rs][3], 0, 0, 0);
      }
    }
  }
  __syncthreads();  // masks dead; smem becomes combine overlay
  gemm_epilogue<RELU, POOL3>(smem, b, it, tid, acc, bias, Hout);

  if (POOL3) {
    __syncthreads();
    if (tid < 64) {
      float v = -3.4e38f;
#pragma unroll
      for (int w = 0; w < 4; ++w)
        v = fmaxf(v, ((const float*)(smem + w * 16384))[tid]);
      part3[((long)b * 32 + it) * 64 + tid] = v;
    }
    // ---- fused tail: last block to finish runs pool finals + head ----
    __threadfence();
    __syncthreads();
    if (tid == 0) s_last = (atomicAdd(done, 1u) == 255u) ? 1 : 0;
    __syncthreads();
    if (s_last) {
      __threadfence();             // acquire: see all blocks' part3
      float* obuf = (float*)smem;  // [8][192] overlay
      const int col = tid;
      const int bb = col >> 6, e = col & 63;
      float m1 = -3.4e38f, m2 = -3.4e38f, m3 = -3.4e38f;
#pragma unroll
      for (int c = 0; c < 32; ++c) {
        m1 = fmaxf(m1, PP1[(long)c * 512 + col]);
        m2 = fmaxf(m2, PP2[(long)c * 512 + col]);
        m3 = fmaxf(m3, part3[((long)bb * 32 + c) * 64 + e]);
      }
      out[bb * 192 + e] = m1;
      out[bb * 192 + 64 + e] = m2;
      out[bb * 192 + 128 + e] = m3;
      obuf[bb * 192 + e] = m1;
      obuf[bb * 192 + 64 + e] = m2;
      obuf[bb * 192 + 128 + e] = m3;
      __syncthreads();
      float a = bmap[e];
#pragma unroll 4
      for (int k = 0; k < 192; ++k) a += obuf[bb * 192 + k] * wmap[k * 64 + e];
      out[1536 + bb * 64 + e] = a;
    }
  }
}

// ---------- kernels 3/5: fused BN + xw_h (+pool partial from b==0 blocks) ----
__global__ __launch_bounds__(256) void k_xwh_bn(const float* __restrict__ H,
                                                const float* __restrict__ w,
                                                unsigned short* __restrict__ xws,
                                                float* __restrict__ PP) {
  __shared__ float hs[64 * 65];
  __shared__ float wsh[64 * 64];
  __shared__ float sm[64], srs[64];
  const int bid = blockIdx.x, tid = threadIdx.x;
  const int jc = bid & 31, b = bid >> 5;
  const int j0 = jc * 64;
  // pass 1: stats. thread t: node n=t>>2, quarter q=t&3 (16 e each, all 8 bb)
  {
    const int n = tid >> 2, q = tid & 3;
    float s1 = 0.f, s2 = 0.f;
#pragma unroll
    for (int bb = 0; bb < 8; ++bb) {
      const float4* hp =
          (const float4*)(H + ((long)bb * NN + j0 + n) * 64 + q * 16);
#pragma unroll
      for (int c = 0; c < 4; ++c) {
        float4 v = hp[c];
        s1 += v.x + v.y + v.z + v.w;
        s2 += v.x * v.x + v.y * v.y + v.z * v.z + v.w * v.w;
      }
    }
    s1 += __shfl_xor(s1, 1);
    s2 += __shfl_xor(s2, 1);
    s1 += __shfl_xor(s1, 2);
    s2 += __shfl_xor(s2, 2);
    if (q == 0) {
      float mean = s1 * (1.0f / 512.0f);
      float var = fmaxf(s2 * (1.0f / 512.0f) - mean * mean, 0.0f);
      sm[n] = mean;
      srs[n] = rsqrtf(var + 1e-5f);
    }
  }
  __syncthreads();
  // pass 2: normalized tile for our b + weights
  for (int idx = tid; idx < 4096; idx += 256) {
    int row = idx >> 6, f = idx & 63;
    float v = H[((long)b * NN + j0 + row) * 64 + f];
    hs[row * 65 + f] = (v - sm[row]) * srs[row];
    wsh[idx] = w[idx];
  }
  __syncthreads();
  // pass 3: xw into swizzled fragment layout (virtual-K position)
  {
    const int j = tid & 63, g = tid >> 6;
    const int V = kvirt(j0 + j);
    const int kblk = V >> 5, kq = (V >> 3) & 3, kj = V & 7;
    unsigned short* dst = xws + (((long)b * 64 + kblk) * 4 + g) * 512 + kj;
    float acc[16];
#pragma unroll
    for (int ii = 0; ii < 16; ++ii) acc[ii] = 0.f;
#pragma unroll
    for (int c = 0; c < 4; ++c) {
      float xr[16];
#pragma unroll
      for (int f = 0; f < 16; ++f) xr[f] = hs[j * 65 + c * 16 + f];
#pragma unroll
      for (int ii = 0; ii < 16; ++ii)
#pragma unroll
        for (int f = 0; f < 16; ++f)
          acc[ii] += xr[f] * wsh[(c * 16 + f) * 64 + g * 16 + ii];
    }
#pragma unroll
    for (int ii = 0; ii < 16; ++ii) dst[(kq * 16 + ii) * 8] = f2bf(acc[ii]);
  }
  // pass 4 (b==0 blocks): pool partials over our 64 nodes, all (bb,e)
  if (b == 0) {
#pragma unroll
    for (int part = 0; part < 2; ++part) {
      const int col = part * 256 + tid;
      const int bb = col >> 6, e = col & 63;
      float mx = -3.4e38f;
      for (int n = 0; n < 64; ++n) {
        float v = H[((long)bb * NN + j0 + n) * 64 + e];
        mx = fmaxf(mx, (v - sm[n]) * srs[n]);
      }
      PP[(long)jc * 512 + col] = mx;
    }
  }
}

extern "C" void kernel_launch(void* const* d_in, const int* in_sizes, int n_in,
                              void* d_out, int out_size, void* d_ws,
                              size_t ws_size, hipStream_t stream) {
  const float* x = (const float*)d_in[0];
  const int* rel = (const int*)d_in[1];
  // d_in[2] (adj) unread: adj == (rel > 0) == union bitplane
  const float* w_first = (const float*)d_in[3];
  const float* b_first = (const float*)d_in[4];
  const float* w_block = (const float*)d_in[5];
  const float* b_block = (const float*)d_in[6];
  const float* w_last = (const float*)d_in[7];
  const float* b_last = (const float*)d_in[8];
  const float* w_map = (const float*)d_in[9];
  const float* b_map = (const float*)d_in[10];
  float* out = (float*)d_out;

  char* ws = (char*)d_ws;
  const size_t MB = 1024 * 1024;
  unsigned* PLANES = (unsigned*)(ws);                     // 16 MiB (4 planes)
  unsigned short* XWS = (unsigned short*)(ws + 16 * MB);  // 6 MiB
  float* H = (float*)(ws + 22 * MB);                      // 4 MiB
  float* PP1 = (float*)(ws + 26 * MB);                    // 64 KiB
  float* PP2 = (float*)(ws + 27 * MB);                    // 64 KiB
  float* PART3 = (float*)(ws + 28 * MB);                  // 64 KiB
  unsigned* DONE = (unsigned*)(ws + 29 * MB);             // 4 B

  // ---- streaming pack (virtual-K, no over-fetch) + XW(layer1) + zero DONE --
  k_pack_xw1<<<4096, 256, 0, stream>>>(rel, PLANES, x, w_first, XWS, DONE);
  // ---- layer 1 (fused bias+L2norm+relu) ----
  k_gemm8<3, true, false><<<256, 512, 0, stream>>>(
      PLANES, XWS, b_first, H, nullptr, nullptr, nullptr, nullptr, nullptr,
      nullptr, nullptr);
  k_xwh_bn<<<256, 256, 0, stream>>>(H, w_block, XWS, PP1);
  // ---- layer 2 ----
  k_gemm8<1, true, false><<<256, 512, 0, stream>>>(
      PLANES, XWS, b_block, H, nullptr, nullptr, nullptr, nullptr, nullptr,
      nullptr, nullptr);
  k_xwh_bn<<<256, 256, 0, stream>>>(H, w_last, XWS, PP2);
  // ---- layer 3 (fused L2norm + pool3 + last-block tail) ----
  k_gemm8<1, false, true><<<256, 512, 0, stream>>>(
      PLANES, XWS, b_last, nullptr, PART3, PP1, PP2, out, w_map, b_map, DONE);
}